// Round 1
// baseline (641.548 us; speedup 1.0000x reference)
//
#include <hip/hip_runtime.h>

#define NN 10000
#define NE 100000

constexpr float TP_NORM = 0.125f;   // 1/sqrt(C*S) = 1/8
constexpr float LG_NORM = 0.125f;   // DOT_NORM * SCALE = 0.25 * 0.5

__device__ __forceinline__ float fsig(float x) { return 1.0f / (1.0f + __expf(-x)); }

__device__ __forceinline__ void load16(const float* __restrict__ p, float* v) {
#pragma unroll
    for (int i = 0; i < 4; ++i) {
        float4 t = reinterpret_cast<const float4*>(p)[i];
        v[4 * i + 0] = t.x; v[4 * i + 1] = t.y; v[4 * i + 2] = t.z; v[4 * i + 3] = t.w;
    }
}

__device__ __forceinline__ void store16(float* __restrict__ p, const float* v, float scale) {
#pragma unroll
    for (int i = 0; i < 4; ++i) {
        float4 t;
        t.x = v[4 * i + 0] * scale; t.y = v[4 * i + 1] * scale;
        t.z = v[4 * i + 2] * scale; t.w = v[4 * i + 3] * scale;
        reinterpret_cast<float4*>(p)[i] = t;
    }
}

// hid = silu(emb @ W1 + b1), W1: [16,64] (uniform scalar-load friendly)
__device__ __forceinline__ void radial_hid(const float* __restrict__ emb,
                                           const float* __restrict__ W1,
                                           const float* __restrict__ b1,
                                           float* __restrict__ hid) {
#pragma unroll
    for (int h = 0; h < 64; ++h) hid[h] = b1[h];
#pragma unroll 1
    for (int i = 0; i < 16; ++i) {
        const float ei = emb[i];
        const float* __restrict__ row = W1 + i * 64;
#pragma unroll
        for (int h = 0; h < 64; ++h) hid[h] = fmaf(ei, row[h], hid[h]);
    }
#pragma unroll
    for (int h = 0; h < 64; ++h) hid[h] = hid[h] * fsig(hid[h]);
}

// acc[k] = sum_{h,c,s} hid[h] * x[c] * sh[s] * W2[h, (c*4+s)*16 + k]
//        + sum_{c,s}   x[c] * sh[s] * b2[(c*4+s)*16 + k]        (un-normalized)
__device__ __forceinline__ void tp_contract(const float* __restrict__ x,
                                            const float* __restrict__ sh,
                                            const float* __restrict__ hid,
                                            const float* __restrict__ W2,
                                            const float* __restrict__ b2,
                                            float* __restrict__ acc) {
#pragma unroll
    for (int k = 0; k < 16; ++k) acc[k] = 0.0f;
    // bias term (b2 is zeros in setup, kept for generality; ~1.5% cost)
#pragma unroll 1
    for (int c = 0; c < 16; ++c) {
#pragma unroll
        for (int s = 0; s < 4; ++s) {
            const float o = x[c] * sh[s];
            const float* __restrict__ bb = b2 + (c * 4 + s) * 16;
#pragma unroll
            for (int k = 0; k < 16; ++k) acc[k] = fmaf(o, bb[k], acc[k]);
        }
    }
    // main contraction: h rolled (keeps icache hot-loop ~1.1k inst), inner fully unrolled
#pragma unroll 1
    for (int h = 0; h < 64; ++h) {
        const float th = hid[h];
        const float* __restrict__ row = W2 + h * 1024;
#pragma unroll
        for (int c = 0; c < 16; ++c) {
            const float thc = th * x[c];
#pragma unroll
            for (int s = 0; s < 4; ++s) {
                const float o = thc * sh[s];
                const float* __restrict__ rr = row + (c * 4 + s) * 16;
#pragma unroll
                for (int k = 0; k < 16; ++k) acc[k] = fmaf(o, rr[k], acc[k]);
            }
        }
    }
}

// K1: q = nf @ Wq ; zero den/agg
__global__ __launch_bounds__(256) void k_prep(const float* __restrict__ nf,
                                              const float* __restrict__ Wq,
                                              float* __restrict__ q,
                                              float* __restrict__ den,
                                              float* __restrict__ agg) {
    const int n = blockIdx.x * 256 + threadIdx.x;
    if (n >= NN) return;
    float xf[16];
    load16(nf + (size_t)n * 16, xf);
    float qq[16];
#pragma unroll
    for (int k = 0; k < 16; ++k) qq[k] = 0.0f;
#pragma unroll 1
    for (int j = 0; j < 16; ++j) {
        const float a = xf[j];
        const float* __restrict__ r = Wq + j * 16;
#pragma unroll
        for (int k = 0; k < 16; ++k) qq[k] = fmaf(a, r[k], qq[k]);
    }
    store16(q + (size_t)n * 16, qq, 1.0f);
    float4 z; z.x = z.y = z.z = z.w = 0.0f;
    reinterpret_cast<float4*>(den + (size_t)n * 4)[0] = z;
#pragma unroll
    for (int i = 0; i < 4; ++i) reinterpret_cast<float4*>(agg + (size_t)n * 16)[i] = z;
}

// K2: fused heavy edge kernel
__global__ __launch_bounds__(64) void k_edge_kernel(
    const float* __restrict__ nf, const float* __restrict__ esh,
    const float* __restrict__ emb_g, const float* __restrict__ elen,
    const float* __restrict__ kW1, const float* __restrict__ kb1,
    const float* __restrict__ kW2, const float* __restrict__ kb2,
    const float* __restrict__ vW1, const float* __restrict__ vb1,
    const float* __restrict__ vW2, const float* __restrict__ vb2,
    const float* __restrict__ Wdot, const int* __restrict__ eidx,
    const float* __restrict__ q,
    float* __restrict__ ex_o, float* __restrict__ ved_o, float* __restrict__ den) {
    const int e = blockIdx.x * 64 + threadIdx.x;
    if (e >= NE) return;
    const int src = eidx[e];
    const int dst = eidx[NE + e];

    float x[16], emb[16], sh[4];
    load16(nf + (size_t)src * 16, x);
    load16(emb_g + (size_t)e * 16, emb);
    {
        float4 t = reinterpret_cast<const float4*>(esh + (size_t)e * 4)[0];
        sh[0] = t.x; sh[1] = t.y; sh[2] = t.z; sh[3] = t.w;
    }

    float hid[64], acc[16];

    // ---- K pass ----
    radial_hid(emb, kW1, kb1, hid);
    tp_contract(x, sh, hid, kW2, kb2, acc);

    // logits -> ex (no max-subtraction: logits are O(1), exp is safe)
    const float len = elen[e];
    const float cut = fsig(10.0f * (1.0f - len * 0.2f));
#pragma unroll
    for (int hh = 0; hh < 4; ++hh) {
        const float* __restrict__ qn = q + (size_t)dst * 16 + hh * 4;
        float l = 0.0f;
#pragma unroll
        for (int j = 0; j < 4; ++j) {
            float u = 0.0f;
#pragma unroll
            for (int i = 0; i < 4; ++i) u = fmaf(qn[i], Wdot[i * 4 + j], u);
            l = fmaf(u, acc[hh * 4 + j] * TP_NORM, l);
        }
        l *= LG_NORM * cut;
        const float ev = __expf(l);
        ex_o[(size_t)e * 4 + hh] = ev;
        atomicAdd(&den[(size_t)dst * 4 + hh], ev);
    }

    // ---- V pass (reuse hid/acc registers) ----
    radial_hid(emb, vW1, vb1, hid);
    tp_contract(x, sh, hid, vW2, vb2, acc);
    store16(ved_o + (size_t)e * 16, acc, TP_NORM);
}

// K3: attn = ex/den[dst]; agg += v_edge * attn
__global__ __launch_bounds__(256) void k_agg(const int* __restrict__ eidx,
                                             const float* __restrict__ ex,
                                             const float* __restrict__ den,
                                             const float* __restrict__ ved,
                                             float* __restrict__ agg) {
    const int e = blockIdx.x * 256 + threadIdx.x;
    if (e >= NE) return;
    const int dst = eidx[NE + e];
    float a[4];
#pragma unroll
    for (int hh = 0; hh < 4; ++hh) a[hh] = ex[(size_t)e * 4 + hh] / den[(size_t)dst * 4 + hh];
    float v[16];
    load16(ved + (size_t)e * 16, v);
#pragma unroll
    for (int i = 0; i < 16; ++i) atomicAdd(&agg[(size_t)dst * 16 + i], v[i] * a[i >> 2]);
}

// K4: attn_out = nf + agg @ W_out; out = attn_out + norm_act(attn_out@Wf1)@Wf2
__global__ __launch_bounds__(256) void k_final(const float* __restrict__ nf,
                                               const float* __restrict__ agg,
                                               const float* __restrict__ Wout,
                                               const float* __restrict__ Wf1,
                                               const float* __restrict__ Wf2,
                                               float* __restrict__ out) {
    const int n = blockIdx.x * 256 + threadIdx.x;
    if (n >= NN) return;
    float ag[16], ao[16];
    load16(agg + (size_t)n * 16, ag);
    load16(nf + (size_t)n * 16, ao);   // identity skip
#pragma unroll 1
    for (int j = 0; j < 16; ++j) {
        const float a = ag[j];
        const float* __restrict__ r = Wout + j * 16;
#pragma unroll
        for (int k = 0; k < 16; ++k) ao[k] = fmaf(a, r[k], ao[k]);
    }
    float h1[32];
#pragma unroll
    for (int m = 0; m < 32; ++m) h1[m] = 0.0f;
#pragma unroll 1
    for (int k = 0; k < 16; ++k) {
        const float a = ao[k];
        const float* __restrict__ r = Wf1 + k * 32;
#pragma unroll
        for (int m = 0; m < 32; ++m) h1[m] = fmaf(a, r[m], h1[m]);
    }
#pragma unroll
    for (int m = 0; m < 32; ++m) h1[m] = h1[m] * fsig(fabsf(h1[m]));  // NormActivation(silu)
    float ff[16];
#pragma unroll
    for (int k = 0; k < 16; ++k) ff[k] = ao[k];  // out = attn_out + ffn
#pragma unroll 1
    for (int m = 0; m < 32; ++m) {
        const float a = h1[m];
        const float* __restrict__ r = Wf2 + m * 16;
#pragma unroll
        for (int k = 0; k < 16; ++k) ff[k] = fmaf(a, r[k], ff[k]);
    }
    store16(out + (size_t)n * 16, ff, 1.0f);
}

extern "C" void kernel_launch(void* const* d_in, const int* in_sizes, int n_in,
                              void* d_out, int out_size, void* d_ws, size_t ws_size,
                              hipStream_t stream) {
    const float* nf   = (const float*)d_in[0];
    const float* esh  = (const float*)d_in[1];
    const float* emb  = (const float*)d_in[2];
    const float* elen = (const float*)d_in[3];
    const float* Wq   = (const float*)d_in[4];
    const float* kW1  = (const float*)d_in[5];
    const float* kb1  = (const float*)d_in[6];
    const float* kW2  = (const float*)d_in[7];
    const float* kb2  = (const float*)d_in[8];
    const float* vW1  = (const float*)d_in[9];
    const float* vb1  = (const float*)d_in[10];
    const float* vW2  = (const float*)d_in[11];
    const float* vb2  = (const float*)d_in[12];
    const float* Wdot = (const float*)d_in[13];
    const float* Wout = (const float*)d_in[14];
    const float* Wf1  = (const float*)d_in[15];
    const float* Wf2  = (const float*)d_in[16];
    const int*   eidx = (const int*)d_in[17];

    float* out = (float*)d_out;
    float* ws  = (float*)d_ws;
    // workspace layout (floats): q[160000] den[40000] agg[160000] ex[400000] ved[1600000]
    float* q   = ws;
    float* den = ws + 160000;
    float* agg = ws + 200000;
    float* ex  = ws + 360000;
    float* ved = ws + 760000;

    hipLaunchKernelGGL(k_prep, dim3((NN + 255) / 256), dim3(256), 0, stream,
                       nf, Wq, q, den, agg);
    hipLaunchKernelGGL(k_edge_kernel, dim3((NE + 63) / 64), dim3(64), 0, stream,
                       nf, esh, emb, elen, kW1, kb1, kW2, kb2,
                       vW1, vb1, vW2, vb2, Wdot, eidx, q, ex, ved, den);
    hipLaunchKernelGGL(k_agg, dim3((NE + 255) / 256), dim3(256), 0, stream,
                       eidx, ex, den, ved, agg);
    hipLaunchKernelGGL(k_final, dim3((NN + 255) / 256), dim3(256), 0, stream,
                       nf, agg, Wout, Wf1, Wf2, out);
}